// Round 9
// baseline (119.107 us; speedup 1.0000x reference)
//
#include <hip/hip_runtime.h>

#define B_SZ 256
#define C_SZ 1152
#define MO   128            // M*O = 8*16
#define CAPS_EPS 1e-8f

// route geometry: 32 c-splits x 32 b-tiles (8 b each), as in rounds 3-6.
#define CSPL 32
#define CRNG (C_SZ / CSPL)  // 36

struct alignas(8) H4 { _Float16 h[4]; };
union PK2 { unsigned int u32; _Float16 h[2]; };

// ---------------------------------------------------------------------------
// K1: u_hat[c,b,mo] fp16 with WIDE (uint4 = 16B/lane) stores.
// grid = 2304 (c = bid>>1, b-half = bid&1), block = 256 = 4 waves.
// Lane l = (bg = l>>4)*16 + (j = l&15): owns mo = j*8..j*8+7 of b-rows
// base + bg. W[c] rows j*8..+7 held in 64 VGPRs (one-time LDS read);
// u LDS-broadcast (round-6 win: no wave-uniform global loads in hot loop).
// Per iter: 2 ds_read_b128 + 64 FMA + pack + ONE uint4 store; wave's 64
// lanes cover 1KB contiguous (fillBuffer-class store pattern; rounds 3-8
// all used 4B/lane stores and were stuck at ~2 TB/s effective).
// Dword layout identical to round 6 (dword k of a row = fp16 mo 2k,2k+1),
// so route/vcalc are unchanged.
__global__ __launch_bounds__(256, 4) void caps_uhat_w(
    const float* __restrict__ u,      // [B,C,8]
    const float* __restrict__ W,      // [C,128,8]
    uint4* __restrict__ uhat)         // [C,B,16] uint4 (= [C,B,128] fp16)
{
    const int bid  = blockIdx.x;
    const int c    = bid >> 1;
    const int half = bid & 1;
    const int tid  = threadIdx.x;
    const int l    = tid & 63;
    const int wv   = tid >> 6;
    const int j    = l & 15;      // mo-block (8 mo values)
    const int bg   = l >> 4;      // b-subgroup 0..3

    __shared__ __align__(16) float W_sh[1024];     // 4 KB, row-major W[c]
    __shared__ __align__(16) float u_sh[128][8];   // 4 KB

    // stage W[c] (fully coalesced: 256 x float4 = 4 KB)
    *reinterpret_cast<float4*>(&W_sh[tid * 4]) =
        *reinterpret_cast<const float4*>(W + (size_t)c * 1024 + tid * 4);
    // stage u[half*128 .. +127][c][0:8] (one-time)
    {
        const int bl = tid >> 1, i0 = (tid & 1) * 4;
        *reinterpret_cast<float4*>(&u_sh[bl][i0]) =
            *reinterpret_cast<const float4*>(
                u + ((size_t)(half * 128 + bl) * C_SZ + c) * 8 + i0);
    }
    __syncthreads();

    // W rows mo = j*8 .. j*8+7 -> 64 VGPRs (one-time; 16-way bank conflict
    // acceptable as prologue cost)
    float w[8][8];
#pragma unroll
    for (int r = 0; r < 8; ++r) {
        const float4 a =
            *reinterpret_cast<const float4*>(&W_sh[(j * 8 + r) * 8]);
        const float4 b4 =
            *reinterpret_cast<const float4*>(&W_sh[(j * 8 + r) * 8 + 4]);
        w[r][0] = a.x;  w[r][1] = a.y;  w[r][2] = a.z;  w[r][3] = a.w;
        w[r][4] = b4.x; w[r][5] = b4.y; w[r][6] = b4.z; w[r][7] = b4.w;
    }

    // lane-linear store base: uint4 idx (c*B + b)*16 + j, b = half*128 +
    // wv*32 + it*4 + bg  ->  wave covers 64 consecutive uint4 = 1 KB.
    uint4* outp =
        uhat + ((size_t)c * B_SZ + half * 128 + wv * 32 + bg) * 16 + j;

#pragma unroll
    for (int it = 0; it < 8; ++it) {
        const int bl = wv * 32 + it * 4 + bg;
        const float4 u0 = *reinterpret_cast<const float4*>(&u_sh[bl][0]);
        const float4 u1 = *reinterpret_cast<const float4*>(&u_sh[bl][4]);
        float h[8];
#pragma unroll
        for (int r = 0; r < 8; ++r)
            h[r] = w[r][0]*u0.x + w[r][1]*u0.y + w[r][2]*u0.z + w[r][3]*u0.w
                 + w[r][4]*u1.x + w[r][5]*u1.y + w[r][6]*u1.z + w[r][7]*u1.w;
        PK2 p0, p1, p2, p3;
        p0.h[0] = (_Float16)h[0]; p0.h[1] = (_Float16)h[1];
        p1.h[0] = (_Float16)h[2]; p1.h[1] = (_Float16)h[3];
        p2.h[0] = (_Float16)h[4]; p2.h[1] = (_Float16)h[5];
        p3.h[0] = (_Float16)h[6]; p3.h[1] = (_Float16)h[7];
        outp[(size_t)it * 64] = make_uint4(p0.u32, p1.u32, p2.u32, p3.u32);
    }
}

// ---------------------------------------------------------------------------
// vcalc: vout = squash(sum_{k<nsplit} part_in[k]) (+ addv if non-null).
// grid = B, block = 128.
__global__ __launch_bounds__(128) void caps_vcalc(
    const float* __restrict__ part_in,  // [nsplit,B,128]
    const float* __restrict__ addv,     // [B,128] or null
    float* __restrict__ vout,           // [B,128]
    int nsplit)
{
    const int b = blockIdx.x, t = threadIdx.x;
    float s = 0.f;
    for (int k = 0; k < nsplit; ++k)
        s += part_in[((size_t)k * B_SZ + b) * MO + t];
    float n2 = s * s;                   // 16-lane group = one m row
    n2 += __shfl_xor(n2, 1);
    n2 += __shfl_xor(n2, 2);
    n2 += __shfl_xor(n2, 4);
    n2 += __shfl_xor(n2, 8);
    float norm = sqrtf(n2);
    float v = (n2 / (1.f + n2)) * s / (norm + CAPS_EPS);
    if (addv) v += addv[(size_t)b * MO + t];
    vout[(size_t)b * MO + t] = v;
}

// ---------------------------------------------------------------------------
// route: one routing pass over materialized u_hat. UNIF=true is the R=0
// pass (uniform weights 1/8, no softmax, vbuf unused).
template <bool UNIF>
__global__ __launch_bounds__(256) void caps_route(
    const H4* __restrict__ uhat,        // [C,B,32]
    const float* __restrict__ vbuf,     // [B,128] (ignored if UNIF)
    float* __restrict__ part_out)       // [CSPL,B,128]
{
    const int bt  = blockIdx.x & 31;
    const int csp = blockIdx.x >> 5;
    const int tid = threadIdx.x;
    const int g   = tid >> 5;
    const int l   = tid & 31;
    const int b   = bt * 8 + g;
    const int mo4 = l * 4;

    float4 v4 = make_float4(0.f, 0.f, 0.f, 0.f);
    if (!UNIF)
        v4 = *reinterpret_cast<const float4*>(vbuf + (size_t)b * MO + mo4);
    float acc[4] = {0.f, 0.f, 0.f, 0.f};

    const int cbeg = csp * CRNG, cend = cbeg + CRNG;
    const H4* base = uhat + (size_t)b * 32 + l;  // stride B_SZ*32 per c

    H4 r0 = base[(size_t)cbeg * B_SZ * 32];
    H4 r1 = base[(size_t)(cbeg + 1) * B_SZ * 32];

    for (int c = cbeg; c < cend; c += 2) {
        H4 n0 = r0, n1 = r1;
        if (c + 2 < cend) {
            n0 = base[(size_t)(c + 2) * B_SZ * 32];
            n1 = base[(size_t)(c + 3) * B_SZ * 32];
        }
#pragma unroll
        for (int q = 0; q < 2; ++q) {
            H4 r = q ? r1 : r0;
            float uh0 = (float)r.h[0], uh1 = (float)r.h[1];
            float uh2 = (float)r.h[2], uh3 = (float)r.h[3];
            float cw;
            if (UNIF) {
                cw = 0.125f;
            } else {
                float uv = uh0 * v4.x + uh1 * v4.y + uh2 * v4.z + uh3 * v4.w;
                uv += __shfl_xor(uv, 1);      // reduce over o-quarters
                uv += __shfl_xor(uv, 2);      // -> uv[m] on 4 lanes
                float mx = fmaxf(uv, __shfl_xor(uv, 4));
                mx = fmaxf(mx, __shfl_xor(mx, 8));
                mx = fmaxf(mx, __shfl_xor(mx, 16));
                float e = expf(uv - mx);
                float den = e;
                den += __shfl_xor(den, 4);
                den += __shfl_xor(den, 8);
                den += __shfl_xor(den, 16);
                cw = e / den;
            }
            acc[0] = fmaf(cw, uh0, acc[0]);
            acc[1] = fmaf(cw, uh1, acc[1]);
            acc[2] = fmaf(cw, uh2, acc[2]);
            acc[3] = fmaf(cw, uh3, acc[3]);
        }
        r0 = n0; r1 = n1;
    }
    *reinterpret_cast<float4*>(part_out + ((size_t)csp * B_SZ + b) * MO + mo4) =
        make_float4(acc[0], acc[1], acc[2], acc[3]);
}

// ---------------------------------------------------------------------------
// Fallback (small-ws): round-1 fused kernel, needs only 384 KB of ws.
template <int R>
__global__ __launch_bounds__(256) void caps_small(
    const float* __restrict__ u, const float* __restrict__ W,
    const float* __restrict__ s_in, const float* __restrict__ v0_in,
    float* __restrict__ s_out, float* __restrict__ v0_out,
    float* __restrict__ out)
{
    const int b = blockIdx.x, tid = threadIdx.x;
    __shared__ float sh_v[8][17];
    __shared__ float sh_part[256][17];

    if (R >= 1) {
        if (tid < 128) {
            float val = s_in[b * 128 + tid];
            float n2 = val * val;
            n2 += __shfl_xor(n2, 1); n2 += __shfl_xor(n2, 2);
            n2 += __shfl_xor(n2, 4); n2 += __shfl_xor(n2, 8);
            float norm = sqrtf(n2);
            float v = (n2 / (1.f + n2)) * val / (norm + CAPS_EPS);
            int m = tid >> 4, o = tid & 15;
            if (R == 1) { v0_out[b * 128 + tid] = v; sh_v[m][o] = v; }
            else        { sh_v[m][o] = v + v0_in[b * 128 + tid]; }
        }
        __syncthreads();
    }
    const int c_local = tid >> 3, m = tid & 7;
    float s_acc[16];
#pragma unroll
    for (int o = 0; o < 16; ++o) s_acc[o] = 0.f;
    for (int cc = 0; cc < C_SZ; cc += 32) {
        const int c = cc + c_local;
        const float4* up = reinterpret_cast<const float4*>(
            u + (size_t)(b * C_SZ + c) * 8);
        float4 u0 = up[0], u1 = up[1];
        float u8[8] = {u0.x, u0.y, u0.z, u0.w, u1.x, u1.y, u1.z, u1.w};
        float uh[16];
        const float4* wp = reinterpret_cast<const float4*>(
            W + (size_t)((c * 8 + m) * 16) * 8);
#pragma unroll
        for (int o = 0; o < 16; ++o) {
            float4 w0 = wp[o * 2], w1 = wp[o * 2 + 1];
            uh[o] = w0.x * u8[0] + w0.y * u8[1] + w0.z * u8[2] + w0.w * u8[3] +
                    w1.x * u8[4] + w1.y * u8[5] + w1.z * u8[6] + w1.w * u8[7];
        }
        float cw;
        if (R == 0) cw = 0.125f;
        else {
            float uv = 0.f;
#pragma unroll
            for (int o = 0; o < 16; ++o) uv = fmaf(uh[o], sh_v[m][o], uv);
            float mx = uv;
            mx = fmaxf(mx, __shfl_xor(mx, 1));
            mx = fmaxf(mx, __shfl_xor(mx, 2));
            mx = fmaxf(mx, __shfl_xor(mx, 4));
            float e = expf(uv - mx);
            float den = e;
            den += __shfl_xor(den, 1); den += __shfl_xor(den, 2);
            den += __shfl_xor(den, 4);
            cw = e / den;
        }
#pragma unroll
        for (int o = 0; o < 16; ++o) s_acc[o] = fmaf(cw, uh[o], s_acc[o]);
    }
#pragma unroll
    for (int o = 0; o < 16; ++o) sh_part[tid][o] = s_acc[o];
    __syncthreads();
    if (tid < 128) {
        const int m2 = tid >> 4, o2 = tid & 15;
        float s = 0.f;
#pragma unroll
        for (int gg = 0; gg < 32; ++gg) s += sh_part[gg * 8 + m2][o2];
        if (R < 2) s_out[b * 128 + tid] = s;
        else {
            float n2 = s * s;
            n2 += __shfl_xor(n2, 1); n2 += __shfl_xor(n2, 2);
            n2 += __shfl_xor(n2, 4); n2 += __shfl_xor(n2, 8);
            float norm = sqrtf(n2);
            out[b * 128 + tid] = (n2 / (1.f + n2)) * s / (norm + CAPS_EPS);
        }
    }
}

extern "C" void kernel_launch(void* const* d_in, const int* in_sizes, int n_in,
                              void* d_out, int out_size, void* d_ws, size_t ws_size,
                              hipStream_t stream) {
    const float* u = (const float*)d_in[0];  // [256,1152,8]
    const float* W = (const float*)d_in[1];  // [1152,8,16,8]
    float* out = (float*)d_out;              // [256,8,16]

    const size_t UHAT_BYTES = (size_t)C_SZ * B_SZ * MO * 2;      // 75.5 MB
    const size_t PR_FLOATS  = (size_t)CSPL * B_SZ * MO;          // 4.2 MB
    const size_t NEED = UHAT_BYTES + (3 * PR_FLOATS + 2 * B_SZ * MO) * 4;

    if (ws_size >= NEED) {
        uint4* uhat_w4   = (uint4*)d_ws;
        const H4* uhat_r = (const H4*)d_ws;
        float* part0 = (float*)((char*)d_ws + UHAT_BYTES);
        float* partA = part0 + PR_FLOATS;
        float* partB = partA + PR_FLOATS;
        float* v0    = partB + PR_FLOATS;
        float* vsum  = v0 + B_SZ * MO;

        dim3 blk(256);
        caps_uhat_w<<<dim3(C_SZ * 2), blk, 0, stream>>>(u, W, uhat_w4);
        caps_route<true ><<<dim3(CSPL * 32), blk, 0, stream>>>(uhat_r, nullptr, part0);
        caps_vcalc<<<dim3(B_SZ), dim3(128), 0, stream>>>(part0, nullptr, v0, CSPL);
        caps_route<false><<<dim3(CSPL * 32), blk, 0, stream>>>(uhat_r, v0, partA);
        caps_vcalc<<<dim3(B_SZ), dim3(128), 0, stream>>>(partA, v0, vsum, CSPL);
        caps_route<false><<<dim3(CSPL * 32), blk, 0, stream>>>(uhat_r, vsum, partB);
        caps_vcalc<<<dim3(B_SZ), dim3(128), 0, stream>>>(partB, nullptr, out, CSPL);
    } else {
        // small-ws fallback (round-1 path)
        float* sA = (float*)d_ws;
        float* sB = sA + 32768;
        float* v0 = sB + 32768;
        dim3 grid(B_SZ), blk(256);
        caps_small<0><<<grid, blk, 0, stream>>>(u, W, nullptr, nullptr, sA, nullptr, nullptr);
        caps_small<1><<<grid, blk, 0, stream>>>(u, W, sA, nullptr, sB, v0, nullptr);
        caps_small<2><<<grid, blk, 0, stream>>>(u, W, sB, v0, nullptr, nullptr, out);
    }
}

// Round 10
// 80.242 us; speedup vs baseline: 1.4843x; 1.4843x over previous
//
#include <hip/hip_runtime.h>

#define B_SZ 256
#define C_SZ 1152
#define MO   128            // M*O = 8*16
#define CAPS_EPS 1e-8f

// Uniform tiling for K1-K3: 32 c-splits x 32 b-tiles, grid 1024.
#define CSPL 32
#define CRNG (C_SZ / CSPL)  // 36 c per block
#define BPB  8              // b per block
#define CPW  (CRNG / 4)     // 9 c per wave

struct alignas(8) H4 { _Float16 h[4]; };
union PK2 { unsigned int u32; _Float16 h[2]; };

// ---------------------------------------------------------------------------
// K1: u_hat (fp16) + fused R0 partial sums.
// grid = 1024 (csp = bid>>5, bt = bid&31), block = 256 = 4 waves.
// Tile = 36 c x 8 b. Wave wv owns c's wv*9..+8; lane l holds W[c] rows
// mo=2l,2l+1 in 16 VGPRs (coalesced float4 loads). u[8b][36c][8] staged in
// LDS once (fully coalesced: 288 contiguous floats per b), hot-loop reads
// are broadcast ds_read_b128 (round-6 win). R0 partial accumulated in regs
// (acc[8][2]) then cross-wave LDS reduce -> part0[csp][b0..b0+7][128]
// (each (csp,b) written by exactly one block).
__global__ __launch_bounds__(256) void caps_uhat_p0(
    const float* __restrict__ u,      // [B,C,8]
    const float* __restrict__ W,      // [C,128,8]
    unsigned int* __restrict__ uhat,  // [C,B,64] dwords (= [C,B,128] fp16)
    float* __restrict__ part0)        // [CSPL,B,128]
{
    const int bid = blockIdx.x;
    const int csp = bid >> 5;
    const int bt  = bid & 31;
    const int c0  = csp * CRNG;
    const int b0  = bt * BPB;
    const int tid = threadIdx.x;
    const int l   = tid & 63;
    const int wv  = tid >> 6;

    __shared__ __align__(16) float u_sh[BPB][292];      // 8 x 288(+4 pad)
    __shared__ __align__(16) float s_lds[4][BPB][MO];   // 16 KB

    // stage u[b0..b0+7][c0..c0+35][0:8]: 8 x 72 float4, fully coalesced rows
    for (int idx = tid; idx < BPB * 72; idx += 256) {
        const int bb = idx / 72, off = idx % 72;
        *reinterpret_cast<float4*>(&u_sh[bb][off * 4]) =
            *reinterpret_cast<const float4*>(
                u + ((size_t)(b0 + bb) * C_SZ + c0) * 8 + off * 4);
    }
    __syncthreads();

    float acc[BPB][2];
#pragma unroll
    for (int bb = 0; bb < BPB; ++bb) { acc[bb][0] = 0.f; acc[bb][1] = 0.f; }

    for (int k = 0; k < CPW; ++k) {
        const int cl = wv * CPW + k;
        const int c  = c0 + cl;
        // W[c] rows mo=2l (wa,wb), mo=2l+1 (wc4,wd): coalesced float4
        const float4* wp =
            reinterpret_cast<const float4*>(W + (size_t)c * 1024) + l * 4;
        const float4 wa = wp[0], wb = wp[1], wc4 = wp[2], wd = wp[3];
        unsigned int* ub = uhat + ((size_t)c * B_SZ + b0) * 64 + l;
        const int cb = cl * 8;
#pragma unroll
        for (int bb = 0; bb < BPB; ++bb) {
            const float4 u0 = *reinterpret_cast<const float4*>(&u_sh[bb][cb]);
            const float4 u1 =
                *reinterpret_cast<const float4*>(&u_sh[bb][cb + 4]);
            float h0 = wa.x*u0.x + wa.y*u0.y + wa.z*u0.z + wa.w*u0.w
                     + wb.x*u1.x + wb.y*u1.y + wb.z*u1.z + wb.w*u1.w;
            float h1 = wc4.x*u0.x + wc4.y*u0.y + wc4.z*u0.z + wc4.w*u0.w
                     + wd.x*u1.x + wd.y*u1.y + wd.z*u1.z + wd.w*u1.w;
            PK2 pk;
            pk.h[0] = (_Float16)h0;
            pk.h[1] = (_Float16)h1;
            ub[(size_t)bb * 64] = pk.u32;   // 256B/wave coalesced
            acc[bb][0] += h0;
            acc[bb][1] += h1;
        }
    }

    // cross-wave reduce of R0 partials (uniform weight 1/8)
#pragma unroll
    for (int bb = 0; bb < BPB; ++bb)
        *reinterpret_cast<float2*>(&s_lds[wv][bb][2 * l]) =
            make_float2(acc[bb][0] * 0.125f, acc[bb][1] * 0.125f);
    __syncthreads();

    {   // 256 threads = 8 b x 32 float4: full [8][128] coverage
        const int bb = tid >> 5, j = tid & 31;
        float4 r = make_float4(0.f, 0.f, 0.f, 0.f);
#pragma unroll
        for (int w = 0; w < 4; ++w) {
            const float4 x =
                *reinterpret_cast<const float4*>(&s_lds[w][bb][4 * j]);
            r.x += x.x; r.y += x.y; r.z += x.z; r.w += x.w;
        }
        *reinterpret_cast<float4*>(
            part0 + ((size_t)csp * B_SZ + b0 + bb) * MO + 4 * j) = r;
    }
}

// ---------------------------------------------------------------------------
// K2/K3: routing pass with FUSED v prologue.
// grid = 1024, same (csp,bt) tiling as K1. Prologue: every block reduces
// part_in over the 32 csp for its 8 b's (128 KB of cache-friendly reads),
// squashes -> v. PASS 1: v = v0, csp==0 blocks persist v0 to ws.
// PASS 2: v = squash(s1) + v0 (= vsum; b-linearity trick).
// Main: old proven route body (group of 32 lanes per b, prefetch depth 2).
template <int PASS>
__global__ __launch_bounds__(256) void caps_route_f(
    const float* __restrict__ part_in,  // [CSPL,B,128]
    float* __restrict__ v0_io,          // [B,128] (out if PASS1, in if PASS2)
    const H4* __restrict__ uhat,        // [C,B,32]
    float* __restrict__ part_out)       // [CSPL,B,128]
{
    const int bid = blockIdx.x;
    const int csp = bid >> 5;
    const int bt  = bid & 31;
    const int c0  = csp * CRNG;
    const int b0  = bt * BPB;
    const int tid = threadIdx.x;

    __shared__ __align__(16) float v_sh[BPB][MO];   // 4 KB

    {   // prologue: thread -> (bb = tid>>5, j = tid&31) owns mo 4j..4j+3
        const int bb = tid >> 5, j = tid & 31;
        float4 s = make_float4(0.f, 0.f, 0.f, 0.f);
        for (int k = 0; k < CSPL; ++k) {
            const float4 x = *reinterpret_cast<const float4*>(
                part_in + ((size_t)k * B_SZ + b0 + bb) * MO + 4 * j);
            s.x += x.x; s.y += x.y; s.z += x.z; s.w += x.w;
        }
        // squash over (b, m = j>>2): 4 threads (j&~3..j|3) hold the 16 o's
        float n2 = s.x*s.x + s.y*s.y + s.z*s.z + s.w*s.w;
        n2 += __shfl_xor(n2, 1);
        n2 += __shfl_xor(n2, 2);
        const float norm = sqrtf(n2);
        const float sc = (n2 / (1.f + n2)) / (norm + CAPS_EPS);
        float4 v = make_float4(s.x * sc, s.y * sc, s.z * sc, s.w * sc);
        if (PASS == 1) {
            if (csp == 0)
                *reinterpret_cast<float4*>(
                    v0_io + (size_t)(b0 + bb) * MO + 4 * j) = v;
        } else {
            const float4 p = *reinterpret_cast<const float4*>(
                v0_io + (size_t)(b0 + bb) * MO + 4 * j);
            v.x += p.x; v.y += p.y; v.z += p.z; v.w += p.w;
        }
        *reinterpret_cast<float4*>(&v_sh[bb][4 * j]) = v;
    }
    __syncthreads();

    // main: group g (32 lanes) owns b = b0+g; lane l owns mo 4l..4l+3
    const int g = tid >> 5;
    const int l = tid & 31;
    const int b = b0 + g;
    const float4 v4 = *reinterpret_cast<const float4*>(&v_sh[g][4 * l]);
    float acc[4] = {0.f, 0.f, 0.f, 0.f};

    const H4* base = uhat + ((size_t)c0 * B_SZ + b) * 32 + l;  // +B*32 per c

    H4 r0 = base[0];
    H4 r1 = base[(size_t)B_SZ * 32];

    for (int cl = 0; cl < CRNG; cl += 2) {
        H4 n0 = r0, n1 = r1;
        if (cl + 2 < CRNG) {
            n0 = base[(size_t)(cl + 2) * B_SZ * 32];
            n1 = base[(size_t)(cl + 3) * B_SZ * 32];
        }
#pragma unroll
        for (int q = 0; q < 2; ++q) {
            const H4 r = q ? r1 : r0;
            const float uh0 = (float)r.h[0], uh1 = (float)r.h[1];
            const float uh2 = (float)r.h[2], uh3 = (float)r.h[3];
            float uv = uh0 * v4.x + uh1 * v4.y + uh2 * v4.z + uh3 * v4.w;
            uv += __shfl_xor(uv, 1);      // reduce over o-quarters
            uv += __shfl_xor(uv, 2);      // -> uv[m] on 4 lanes
            float mx = fmaxf(uv, __shfl_xor(uv, 4));
            mx = fmaxf(mx, __shfl_xor(mx, 8));
            mx = fmaxf(mx, __shfl_xor(mx, 16));
            const float e = expf(uv - mx);
            float den = e;
            den += __shfl_xor(den, 4);
            den += __shfl_xor(den, 8);
            den += __shfl_xor(den, 16);
            const float cw = e / den;
            acc[0] = fmaf(cw, uh0, acc[0]);
            acc[1] = fmaf(cw, uh1, acc[1]);
            acc[2] = fmaf(cw, uh2, acc[2]);
            acc[3] = fmaf(cw, uh3, acc[3]);
        }
        r0 = n0; r1 = n1;
    }
    *reinterpret_cast<float4*>(
        part_out + ((size_t)csp * B_SZ + b) * MO + 4 * l) =
        make_float4(acc[0], acc[1], acc[2], acc[3]);
}

// ---------------------------------------------------------------------------
// K4: vout = squash(sum_{k<nsplit} part_in[k]). grid = B, block = 128.
__global__ __launch_bounds__(128) void caps_vcalc(
    const float* __restrict__ part_in,  // [nsplit,B,128]
    float* __restrict__ vout,           // [B,128]
    int nsplit)
{
    const int b = blockIdx.x, t = threadIdx.x;
    float s = 0.f;
    for (int k = 0; k < nsplit; ++k)
        s += part_in[((size_t)k * B_SZ + b) * MO + t];
    float n2 = s * s;                   // 16-lane group = one m row
    n2 += __shfl_xor(n2, 1);
    n2 += __shfl_xor(n2, 2);
    n2 += __shfl_xor(n2, 4);
    n2 += __shfl_xor(n2, 8);
    const float norm = sqrtf(n2);
    vout[(size_t)b * MO + t] = (n2 / (1.f + n2)) * s / (norm + CAPS_EPS);
}

// ---------------------------------------------------------------------------
// Fallback (small-ws): round-1 fused kernel, needs only 384 KB of ws.
template <int R>
__global__ __launch_bounds__(256) void caps_small(
    const float* __restrict__ u, const float* __restrict__ W,
    const float* __restrict__ s_in, const float* __restrict__ v0_in,
    float* __restrict__ s_out, float* __restrict__ v0_out,
    float* __restrict__ out)
{
    const int b = blockIdx.x, tid = threadIdx.x;
    __shared__ float sh_v[8][17];
    __shared__ float sh_part[256][17];

    if (R >= 1) {
        if (tid < 128) {
            float val = s_in[b * 128 + tid];
            float n2 = val * val;
            n2 += __shfl_xor(n2, 1); n2 += __shfl_xor(n2, 2);
            n2 += __shfl_xor(n2, 4); n2 += __shfl_xor(n2, 8);
            float norm = sqrtf(n2);
            float v = (n2 / (1.f + n2)) * val / (norm + CAPS_EPS);
            int m = tid >> 4, o = tid & 15;
            if (R == 1) { v0_out[b * 128 + tid] = v; sh_v[m][o] = v; }
            else        { sh_v[m][o] = v + v0_in[b * 128 + tid]; }
        }
        __syncthreads();
    }
    const int c_local = tid >> 3, m = tid & 7;
    float s_acc[16];
#pragma unroll
    for (int o = 0; o < 16; ++o) s_acc[o] = 0.f;
    for (int cc = 0; cc < C_SZ; cc += 32) {
        const int c = cc + c_local;
        const float4* up = reinterpret_cast<const float4*>(
            u + (size_t)(b * C_SZ + c) * 8);
        float4 u0 = up[0], u1 = up[1];
        float u8[8] = {u0.x, u0.y, u0.z, u0.w, u1.x, u1.y, u1.z, u1.w};
        float uh[16];
        const float4* wp = reinterpret_cast<const float4*>(
            W + (size_t)((c * 8 + m) * 16) * 8);
#pragma unroll
        for (int o = 0; o < 16; ++o) {
            float4 w0 = wp[o * 2], w1 = wp[o * 2 + 1];
            uh[o] = w0.x * u8[0] + w0.y * u8[1] + w0.z * u8[2] + w0.w * u8[3] +
                    w1.x * u8[4] + w1.y * u8[5] + w1.z * u8[6] + w1.w * u8[7];
        }
        float cw;
        if (R == 0) cw = 0.125f;
        else {
            float uv = 0.f;
#pragma unroll
            for (int o = 0; o < 16; ++o) uv = fmaf(uh[o], sh_v[m][o], uv);
            float mx = uv;
            mx = fmaxf(mx, __shfl_xor(mx, 1));
            mx = fmaxf(mx, __shfl_xor(mx, 2));
            mx = fmaxf(mx, __shfl_xor(mx, 4));
            float e = expf(uv - mx);
            float den = e;
            den += __shfl_xor(den, 1); den += __shfl_xor(den, 2);
            den += __shfl_xor(den, 4);
            cw = e / den;
        }
#pragma unroll
        for (int o = 0; o < 16; ++o) s_acc[o] = fmaf(cw, uh[o], s_acc[o]);
    }
#pragma unroll
    for (int o = 0; o < 16; ++o) sh_part[tid][o] = s_acc[o];
    __syncthreads();
    if (tid < 128) {
        const int m2 = tid >> 4, o2 = tid & 15;
        float s = 0.f;
#pragma unroll
        for (int gg = 0; gg < 32; ++gg) s += sh_part[gg * 8 + m2][o2];
        if (R < 2) s_out[b * 128 + tid] = s;
        else {
            float n2 = s * s;
            n2 += __shfl_xor(n2, 1); n2 += __shfl_xor(n2, 2);
            n2 += __shfl_xor(n2, 4); n2 += __shfl_xor(n2, 8);
            float norm = sqrtf(n2);
            out[b * 128 + tid] = (n2 / (1.f + n2)) * s / (norm + CAPS_EPS);
        }
    }
}

extern "C" void kernel_launch(void* const* d_in, const int* in_sizes, int n_in,
                              void* d_out, int out_size, void* d_ws, size_t ws_size,
                              hipStream_t stream) {
    const float* u = (const float*)d_in[0];  // [256,1152,8]
    const float* W = (const float*)d_in[1];  // [1152,8,16,8]
    float* out = (float*)d_out;              // [256,8,16]

    const size_t UHAT_BYTES = (size_t)C_SZ * B_SZ * MO * 2;      // 75.5 MB
    const size_t PR_FLOATS  = (size_t)CSPL * B_SZ * MO;          // 4.2 MB
    const size_t NEED = UHAT_BYTES + (2 * PR_FLOATS + B_SZ * MO) * 4;

    if (ws_size >= NEED) {
        unsigned int* uhat_w = (unsigned int*)d_ws;
        const H4* uhat_r = (const H4*)d_ws;
        float* part0 = (float*)((char*)d_ws + UHAT_BYTES);  // also pass-2 out
        float* partA = part0 + PR_FLOATS;
        float* v0    = partA + PR_FLOATS;

        dim3 blk(256), grid(CSPL * 32);
        caps_uhat_p0 <<<grid, blk, 0, stream>>>(u, W, uhat_w, part0);
        caps_route_f<1><<<grid, blk, 0, stream>>>(part0, v0, uhat_r, partA);
        caps_route_f<2><<<grid, blk, 0, stream>>>(partA, v0, uhat_r, part0);
        caps_vcalc<<<dim3(B_SZ), dim3(128), 0, stream>>>(part0, out, CSPL);
    } else {
        // small-ws fallback (round-1 path)
        float* sA = (float*)d_ws;
        float* sB = sA + 32768;
        float* v0 = sB + 32768;
        dim3 grid(B_SZ), blk(256);
        caps_small<0><<<grid, blk, 0, stream>>>(u, W, nullptr, nullptr, sA, nullptr, nullptr);
        caps_small<1><<<grid, blk, 0, stream>>>(u, W, sA, nullptr, sB, v0, nullptr);
        caps_small<2><<<grid, blk, 0, stream>>>(u, W, sB, v0, nullptr, nullptr, out);
    }
}